// Round 7
// baseline (329.484 us; speedup 1.0000x reference)
//
#include <hip/hip_runtime.h>
#include <cmath>

#define DEV static __device__ __forceinline__

namespace {

constexpr int B = 2, S = 512, D = 512, H = 8;  // dh = 64
constexpr int BS = B * S;                      // 1024 token rows
constexpr float EPSF = 1e-5f;
constexpr float MAXN = 1.0f - 1e-3f;           // MAX_NORM / sqrt(c)
constexpr int NSPLIT = 4;                      // K-splits in attention
constexpr int NBLK = 512;                      // persistent blocks (2/CU)

typedef unsigned short u16;
typedef unsigned int u32;
typedef __attribute__((ext_vector_type(8))) short bf8_t;    // bf16x8 (16B)
typedef __attribute__((ext_vector_type(8))) _Float16 h8_t;  // f16x8
typedef __attribute__((ext_vector_type(4))) float f4_t;

DEV float waveSum(float v) {
#pragma unroll
  for (int o = 32; o > 0; o >>= 1) v += __shfl_xor(v, o, 64);
  return v;
}
DEV u16 f2bf(float f) {  // RNE bf16
  u32 x = __float_as_uint(f);
  u32 r = x + 0x7fffu + ((x >> 16) & 1u);
  return (u16)(r >> 16);
}
DEV float bf2f(u16 u) { return __uint_as_float(((u32)u) << 16); }
DEV u16 f2h(float f) {
  _Float16 h = (_Float16)f;
  u16 u;
  __builtin_memcpy(&u, &h, 2);
  return u;
}
DEV float tanh_pos(float n) {  // tanh for n >= 0
  float e = __builtin_amdgcn_exp2f(2.8853900817779268f * n);  // e^(2n)
  return (e - 1.f) / (e + 1.f);
}
DEV bf8_t conv8(float4 a, float4 b, float f) {
  bf8_t o;
  o[0] = (short)f2bf(a.x * f); o[1] = (short)f2bf(a.y * f);
  o[2] = (short)f2bf(a.z * f); o[3] = (short)f2bf(a.w * f);
  o[4] = (short)f2bf(b.x * f); o[5] = (short)f2bf(b.y * f);
  o[6] = (short)f2bf(b.z * f); o[7] = (short)f2bf(b.w * f);
  return o;
}

// Device-scope grid barrier: agent-scoped atomics give cross-XCD
// release/acquire (L2 writeback/invalidate). Spin bailout avoids hangs.
DEV void gridBarrier(u32* bar, u32 gen) {
  __syncthreads();
  if (threadIdx.x == 0) {
    __threadfence();
    u32 prev = __hip_atomic_fetch_add(&bar[0], 1u, __ATOMIC_ACQ_REL,
                                      __HIP_MEMORY_SCOPE_AGENT);
    if (prev == NBLK - 1) {
      __hip_atomic_store(&bar[0], 0u, __ATOMIC_RELAXED,
                         __HIP_MEMORY_SCOPE_AGENT);
      __hip_atomic_store(&bar[1], gen, __ATOMIC_RELEASE,
                         __HIP_MEMORY_SCOPE_AGENT);
    } else {
      int spins = 0;
      while (__hip_atomic_load(&bar[1], __ATOMIC_ACQUIRE,
                               __HIP_MEMORY_SCOPE_AGENT) < gen) {
        __builtin_amdgcn_s_sleep(4);
        if (++spins > (1 << 22)) break;  // bounded: no harness hang
      }
    }
  }
  __syncthreads();
}

__global__ __launch_bounds__(256, 2) void mega(
    const float* __restrict__ q, const float* __restrict__ k,
    const float* __restrict__ v, const float* __restrict__ Wq,
    const float* __restrict__ bq, const float* __restrict__ Wk,
    const float* __restrict__ bk, const float* __restrict__ Wv,
    const float* __restrict__ bv, const float* __restrict__ Wo,
    const float* __restrict__ bo, float* __restrict__ out,
    u32* __restrict__ bar, float* __restrict__ facs,
    u16* __restrict__ hq, u16* __restrict__ hk, u16* __restrict__ vT,
    float* __restrict__ qn2, float* __restrict__ kn2, u16* __restrict__ ctx,
    float* __restrict__ olin, float* __restrict__ Opart,
    float* __restrict__ rpart) {
  const int blk = blockIdx.x, tid = threadIdx.x;
  __shared__ __align__(16) u16 SL[8192];  // 16 KB, reused per phase
  __shared__ float red[4];

  // ---------- P1: logmap0 row norms -> facs[slab*1024 + row] ----------
  {
    const int w = tid >> 6, l = tid & 63;
#pragma unroll
    for (int pass = 0; pass < 2; ++pass) {
      const int r6 = pass * 4 + w;
      if (r6 < 6) {
        const int gr = blk * 6 + r6;  // 0..3071
        const int slab = gr >> 10, row = gr & 1023;
        const float* in = slab == 0 ? q : (slab == 1 ? k : v);
        const float4* p = (const float4*)(in + (size_t)row * D + l * 8);
        float4 t0 = p[0], t1 = p[1];
        float ss = t0.x * t0.x + t0.y * t0.y + t0.z * t0.z + t0.w * t0.w +
                   t1.x * t1.x + t1.y * t1.y + t1.z * t1.z + t1.w * t1.w;
        ss = waveSum(ss);
        if (l == 0) {
          float n = fmaxf(sqrtf(ss), EPSF);
          float zc = fminf(n, 1.0f - EPSF);
          facs[gr] = 0.34657359027997264f *
                     __builtin_amdgcn_logf((1.0f + zc) / (1.0f - zc)) / n;
        }
      }
    }
  }
  gridBarrier(bar, 1);

  // ---------- P2: QKV GEMM (384 tiles) + expmap / vT epilogues ----------
  if (blk < 384) {
    const int z = blk >> 7, rem2 = blk & 127;
    const int h = rem2 & 7, i0 = (rem2 >> 3) << 6, j0 = h * 64;
    const float* A = z == 0 ? q : (z == 1 ? k : v);
    const float* W = z == 0 ? Wq : (z == 1 ? Wk : Wv);
    const float* bias = z == 0 ? bq : (z == 1 ? bk : bv);
    const int w = tid >> 6, l = tid & 63, lg = l >> 4, lr = l & 15;
    const int srow = tid >> 3, scb = tid & 7;
    const float f0 = facs[z * 1024 + i0 + srow];
    const float f1 = facs[z * 1024 + i0 + srow + 32];
    u16* As = SL;
    u16* Bs = SL + 4096;
    f4_t acc[4] = {{0, 0, 0, 0}, {0, 0, 0, 0}, {0, 0, 0, 0}, {0, 0, 0, 0}};
    for (int kt = 0; kt < D; kt += 64) {
      const float* ap0 = A + (size_t)(i0 + srow) * D + kt + scb * 8;
      const float* ap1 = ap0 + (size_t)32 * D;
      const float* wp0 = W + (size_t)(j0 + srow) * D + kt + scb * 8;
      const float* wp1 = wp0 + (size_t)32 * D;
      float4 a00 = *(const float4*)ap0, a01 = *(const float4*)(ap0 + 4);
      float4 a10 = *(const float4*)ap1, a11 = *(const float4*)(ap1 + 4);
      float4 w00 = *(const float4*)wp0, w01 = *(const float4*)(wp0 + 4);
      float4 w10 = *(const float4*)wp1, w11 = *(const float4*)(wp1 + 4);
      __syncthreads();
      const int sw = 8 * (scb ^ (srow & 7));
      *(bf8_t*)&As[srow * 64 + sw] = conv8(a00, a01, f0);
      *(bf8_t*)&As[(srow + 32) * 64 + sw] = conv8(a10, a11, f1);
      *(bf8_t*)&Bs[srow * 64 + sw] = conv8(w00, w01, 1.f);
      *(bf8_t*)&Bs[(srow + 32) * 64 + sw] = conv8(w10, w11, 1.f);
      __syncthreads();
#pragma unroll
      for (int ks = 0; ks < 2; ++ks) {
        const int arow = w * 16 + lr;
        bf8_t af = *(const bf8_t*)&As[arow * 64 + 8 * ((ks * 4 + lg) ^ (arow & 7))];
#pragma unroll
        for (int nf = 0; nf < 4; ++nf) {
          const int brow = nf * 16 + lr;
          bf8_t bfr = *(const bf8_t*)&Bs[brow * 64 + 8 * ((ks * 4 + lg) ^ (brow & 7))];
          acc[nf] = __builtin_amdgcn_mfma_f32_16x16x32_bf16(af, bfr, acc[nf], 0, 0, 0);
        }
      }
    }
    float c[4][4];
#pragma unroll
    for (int nf = 0; nf < 4; ++nf) {
      const float bb = bias[j0 + nf * 16 + lr];
#pragma unroll
      for (int r = 0; r < 4; ++r) c[nf][r] = acc[nf][r] + bb;
    }
    if (z < 2) {
      float part[4] = {0, 0, 0, 0};
#pragma unroll
      for (int nf = 0; nf < 4; ++nf)
#pragma unroll
        for (int r = 0; r < 4; ++r) part[r] += c[nf][r] * c[nf][r];
#pragma unroll
      for (int off = 1; off < 16; off <<= 1)
#pragma unroll
        for (int r = 0; r < 4; ++r) part[r] += __shfl_xor(part[r], off, 64);
      float fac[4];
#pragma unroll
      for (int r = 0; r < 4; ++r) {
        float n = fmaxf(sqrtf(part[r]), EPSF);
        fac[r] = fminf(tanh_pos(n), MAXN) / n;
      }
      u16 yb[4][4];
      float p2[4] = {0, 0, 0, 0};
#pragma unroll
      for (int nf = 0; nf < 4; ++nf)
#pragma unroll
        for (int r = 0; r < 4; ++r) {
          u16 t = f2bf(c[nf][r] * fac[r]);
          yb[nf][r] = t;
          float yf = bf2f(t);
          p2[r] += yf * yf;  // norm^2 of the rounded point
        }
#pragma unroll
      for (int off = 1; off < 16; off <<= 1)
#pragma unroll
        for (int r = 0; r < 4; ++r) p2[r] += __shfl_xor(p2[r], off, 64);
      u16* dst = z == 0 ? hq : hk;
      float* n2o = z == 0 ? qn2 : kn2;
#pragma unroll
      for (int nf = 0; nf < 4; ++nf)
#pragma unroll
        for (int r = 0; r < 4; ++r)
          dst[(size_t)(i0 + w * 16 + lg * 4 + r) * D + j0 + nf * 16 + lr] = yb[nf][r];
      if (lr == 0)
#pragma unroll
        for (int r = 0; r < 4; ++r)
          n2o[h * BS + i0 + w * 16 + lg * 4 + r] = p2[r];
    } else {
      // V: f16, transpose via LDS -> vT[(b*8+h)*64 + d][s]
      __syncthreads();
#pragma unroll
      for (int nf = 0; nf < 4; ++nf)
#pragma unroll
        for (int r = 0; r < 4; ++r) {
          const int prow = w * 16 + lg * 4 + r;  // local token s
          const int pcol = nf * 16 + lr;         // local d
          As[prow * 64 + 8 * ((pcol >> 3) ^ (prow & 7)) + (pcol & 7)] = f2h(c[nf][r]);
        }
      __syncthreads();
      const int d = tid >> 2, s0 = (tid & 3) * 16;
      const int b = i0 >> 9, sb = (i0 & 511) + s0;
      bf8_t o0, o1;
#pragma unroll
      for (int j = 0; j < 8; ++j) {
        const int s = s0 + j;
        o0[j] = (short)As[s * 64 + 8 * ((d >> 3) ^ (s & 7)) + (d & 7)];
      }
#pragma unroll
      for (int j = 0; j < 8; ++j) {
        const int s = s0 + 8 + j;
        o1[j] = (short)As[s * 64 + 8 * ((d >> 3) ^ (s & 7)) + (d & 7)];
      }
      u16* dst = vT + ((size_t)((b * 8 + h) * 64 + d)) * S + sb;
      *(bf8_t*)dst = o0;
      *(bf8_t*)(dst + 8) = o1;
    }
  }
  gridBarrier(bar, 2);

  // ---------- P3: attention, split-K x4, one 16-row unit per wave ----------
  {
    const int w = tid >> 6, l = tid & 63, lg = l >> 4, lr = l & 15;
    const int u = blk * 4 + w;  // 0..2047
    const int bh = u >> 7, rem = u & 127, sp = rem >> 5, i0q = (rem & 31) * 16;
    const int b = bh >> 3, h = bh & 7;
    u16* Psb = &SL[w * 2048];
    bf8_t qf[2];
#pragma unroll
    for (int ks = 0; ks < 2; ++ks)
      qf[ks] = *(const bf8_t*)(hq + (size_t)(b * S + i0q + lr) * D + h * 64 +
                               ks * 32 + lg * 8);
    float qq[4];
#pragma unroll
    for (int r = 0; r < 4; ++r) qq[r] = qn2[h * BS + b * S + i0q + lg * 4 + r];
    f4_t acc_o[4] = {{0, 0, 0, 0}, {0, 0, 0, 0}, {0, 0, 0, 0}, {0, 0, 0, 0}};
    float rsum[4] = {0, 0, 0, 0};
#pragma unroll
    for (int t = 0; t < 2; ++t) {
      const int kt = sp * 2 + t;
      const int kb = b * S + kt * 64;
      bf8_t kf[2][4], vf[2][4];
#pragma unroll
      for (int ks = 0; ks < 2; ++ks)
#pragma unroll
        for (int nf = 0; nf < 4; ++nf) {
          kf[ks][nf] = *(const bf8_t*)(hk + (size_t)(kb + nf * 16 + lr) * D +
                                       h * 64 + ks * 32 + lg * 8);
          vf[ks][nf] = *(const bf8_t*)(vT + (size_t)(bh * 64 + nf * 16 + lr) * S +
                                       kt * 64 + ks * 32 + lg * 8);
        }
      float kn[4];
#pragma unroll
      for (int nf = 0; nf < 4; ++nf) kn[nf] = kn2[h * BS + kb + nf * 16 + lr];
      f4_t sa[4] = {{0, 0, 0, 0}, {0, 0, 0, 0}, {0, 0, 0, 0}, {0, 0, 0, 0}};
#pragma unroll
      for (int ks = 0; ks < 2; ++ks)
#pragma unroll
        for (int nf = 0; nf < 4; ++nf)
          sa[nf] = __builtin_amdgcn_mfma_f32_16x16x32_bf16(qf[ks], kf[ks][nf],
                                                           sa[nf], 0, 0, 0);
      u16* Pb = Psb + t * 1024;
      float ps[4] = {0, 0, 0, 0};
#pragma unroll
      for (int nf = 0; nf < 4; ++nf) {
        const float kk = kn[nf];
#pragma unroll
        for (int r = 0; r < 4; ++r) {
          const float tt = sa[nf][r];
          float num = fmaxf(qq[r] - 2.f * tt + kk, 0.f);
          float den = fmaxf(1.f - 2.f * tt + qq[r] * kk, EPSF);
          float rr = fminf(fmaxf(sqrtf(num / den), EPSF), MAXN);
          // p = ((1-r)/(1+r))^(1/8)
          float p = __builtin_amdgcn_exp2f(
              0.125f * __builtin_amdgcn_logf((1.f - rr) / (1.f + rr)));
          ps[r] += p;
          const int prow = lg * 4 + r, pcol = nf * 16 + lr;
          Pb[prow * 64 + 8 * ((pcol >> 3) ^ (prow & 7)) + (pcol & 7)] = f2h(p);
        }
      }
#pragma unroll
      for (int off = 1; off < 16; off <<= 1)
#pragma unroll
        for (int r = 0; r < 4; ++r) ps[r] += __shfl_xor(ps[r], off, 64);
#pragma unroll
      for (int r = 0; r < 4; ++r) rsum[r] += ps[r];
#pragma unroll
      for (int ks = 0; ks < 2; ++ks) {
        h8_t pa = *(const h8_t*)&Pb[lr * 64 + 8 * ((ks * 4 + lg) ^ (lr & 7))];
#pragma unroll
        for (int nf = 0; nf < 4; ++nf)
          acc_o[nf] = __builtin_amdgcn_mfma_f32_16x16x32_f16(pa, vf[ks][nf],
                                                             acc_o[nf], 0, 0, 0);
      }
    }
    float* Ob = Opart + ((size_t)(sp * 16 + bh) * S + i0q) * 64;
#pragma unroll
    for (int nf = 0; nf < 4; ++nf)
#pragma unroll
      for (int r = 0; r < 4; ++r)
        Ob[(lg * 4 + r) * 64 + nf * 16 + lr] = acc_o[nf][r];
    if (lr == 0)
#pragma unroll
      for (int r = 0; r < 4; ++r)
        rpart[(size_t)(sp * 16 + bh) * S + i0q + lg * 4 + r] = rsum[r];
  }
  gridBarrier(bar, 3);

  // ---------- P4: combine split-K partials -> ctx bf16 ----------
  {
    const int e = (blk * 256 + tid) * 4;  // 0..524284
    const int bh = e >> 15;
    const int rem = e & 32767;
    const int qrow = rem >> 6, d = rem & 63;
    float rt = 0.f;
#pragma unroll
    for (int sp = 0; sp < NSPLIT; ++sp)
      rt += rpart[(size_t)(sp * 16 + bh) * S + qrow];
    float ox = 0.f, oy = 0.f, oz = 0.f, ow = 0.f;
#pragma unroll
    for (int sp = 0; sp < NSPLIT; ++sp) {
      float4 t = *(const float4*)&Opart[((size_t)(sp * 16 + bh) * S + qrow) * 64 + d];
      ox += t.x; oy += t.y; oz += t.z; ow += t.w;
    }
    float inv = 1.f / rt;
    ushort4 ov;
    ov.x = f2bf(ox * inv); ov.y = f2bf(oy * inv);
    ov.z = f2bf(oz * inv); ov.w = f2bf(ow * inv);
    const int token = (bh >> 3) * S + qrow, col = (bh & 7) * 64 + d;
    *(ushort4*)&ctx[(size_t)token * D + col] = ov;
  }
  gridBarrier(bar, 4);

  // ---------- P5: out projection, 32x32 tiles (512 tiles, all blocks) ------
  {
    const int i0 = (blk >> 4) * 32, j0 = (blk & 15) * 32;
    const int w = tid >> 6, l = tid & 63, lg = l >> 4, lr = l & 15;
    const int srow = tid >> 3, scb = tid & 7;
    u16* As = SL;
    u16* Bs = SL + 2048;
    f4_t acc = {0, 0, 0, 0};
    for (int kt = 0; kt < D; kt += 64) {
      bf8_t a0 = *(const bf8_t*)(ctx + (size_t)(i0 + srow) * D + kt + scb * 8);
      const float* wp = Wo + (size_t)(j0 + srow) * D + kt + scb * 8;
      float4 w00 = *(const float4*)wp, w01 = *(const float4*)(wp + 4);
      __syncthreads();
      const int sw = 8 * (scb ^ (srow & 7));
      *(bf8_t*)&As[srow * 64 + sw] = a0;
      *(bf8_t*)&Bs[srow * 64 + sw] = conv8(w00, w01, 1.f);
      __syncthreads();
#pragma unroll
      for (int ks = 0; ks < 2; ++ks) {
        const int arow = (w >> 1) * 16 + lr;
        const int brow = (w & 1) * 16 + lr;
        bf8_t af = *(const bf8_t*)&As[arow * 64 + 8 * ((ks * 4 + lg) ^ (arow & 7))];
        bf8_t bfr = *(const bf8_t*)&Bs[brow * 64 + 8 * ((ks * 4 + lg) ^ (brow & 7))];
        acc = __builtin_amdgcn_mfma_f32_16x16x32_bf16(af, bfr, acc, 0, 0, 0);
      }
    }
    const int j = j0 + (w & 1) * 16 + lr;
    const float bb = bo[j];
#pragma unroll
    for (int r = 0; r < 4; ++r) {
      const int i = i0 + (w >> 1) * 16 + lg * 4 + r;
      olin[(size_t)i * D + j] = acc[r] + bb;
    }
  }
  gridBarrier(bar, 5);

  // ---------- P6: final expmap0 rows -> d_out ----------
  {
    const int half = tid >> 7, l7 = tid & 127;
    const int row = blk * 2 + half;
    const float4* p = (const float4*)(olin + (size_t)row * D + l7 * 4);
    float4 t = *p;
    float ss = t.x * t.x + t.y * t.y + t.z * t.z + t.w * t.w;
    ss = waveSum(ss);
    if ((tid & 63) == 0) red[tid >> 6] = ss;
    __syncthreads();
    float tot = red[half * 2] + red[half * 2 + 1];
    float n = fmaxf(sqrtf(tot), EPSF);
    float fac = fminf(tanh_pos(n), MAXN) / n;
    float4 o = make_float4(t.x * fac, t.y * fac, t.z * fac, t.w * fac);
    *(float4*)(out + (size_t)row * D + l7 * 4) = o;
  }
}

}  // namespace

extern "C" void kernel_launch(void* const* d_in, const int* in_sizes, int n_in,
                              void* d_out, int out_size, void* d_ws,
                              size_t ws_size, hipStream_t stream) {
  const float* q = (const float*)d_in[0];
  const float* k = (const float*)d_in[1];
  const float* v = (const float*)d_in[2];
  const float* Wq = (const float*)d_in[3];
  const float* bq = (const float*)d_in[4];
  const float* Wk = (const float*)d_in[5];
  const float* bk = (const float*)d_in[6];
  const float* Wv = (const float*)d_in[7];
  const float* bv = (const float*)d_in[8];
  const float* Wo = (const float*)d_in[9];
  const float* bo = (const float*)d_in[10];
  float* out = (float*)d_out;

  char* w8 = (char*)d_ws;
  u32* bar = (u32*)(w8 + 0);                // 256 B (count, release)
  float* facs = (float*)(w8 + 256);         // 12 KB  [3][1024]
  float* qn2 = (float*)(w8 + 16384);        // 32 KB  [H][BS]
  float* kn2 = (float*)(w8 + 49152);        // 32 KB  [H][BS]
  u16* hq = (u16*)(w8 + 81920);             // 1 MB
  u16* hk = (u16*)(w8 + 1130496);           // 1 MB
  u16* vT = (u16*)(w8 + 2179072);           // 1 MB  [bh*64+d][s] f16
  u16* ctx = (u16*)(w8 + 3227648);          // 1 MB  bf16
  float* olin = (float*)(w8 + 4276224);     // 2 MB  fp32
  float* Opart = (float*)(w8 + 6373376);    // 8 MB  [NSPLIT][16][512][64]
  float* rpart = (float*)(w8 + 14761984);   // 128 KB [NSPLIT][16][512]

  hipMemsetAsync(bar, 0, 256, stream);  // barrier state reset each call
  mega<<<NBLK, 256, 0, stream>>>(q, k, v, Wq, bq, Wk, bk, Wv, bv, Wo, bo, out,
                                 bar, facs, hq, hk, vT, qn2, kn2, ctx, olin,
                                 Opart, rpart);
}

// Round 9
// 68.343 us; speedup vs baseline: 4.8210x; 4.8210x over previous
//
#include <hip/hip_runtime.h>
#include <cmath>

#define DEV static __device__ __forceinline__

namespace {

constexpr int B = 2, S = 512, D = 512, H = 8;  // dh = 64
constexpr int BS = B * S;                      // 1024 token rows
constexpr float EPSF = 1e-5f;
constexpr float MAXN = 1.0f - 1e-3f;           // MAX_NORM / sqrt(c)
constexpr int NSPLIT = 4;                      // K-splits in attention

typedef unsigned short u16;
typedef unsigned int u32;
typedef __attribute__((ext_vector_type(8))) short bf8_t;    // bf16x8 (16B)
typedef __attribute__((ext_vector_type(8))) _Float16 h8_t;  // f16x8
typedef __attribute__((ext_vector_type(4))) float f4_t;

DEV float waveSum(float v) {
#pragma unroll
  for (int o = 32; o > 0; o >>= 1) v += __shfl_xor(v, o, 64);
  return v;
}
DEV u16 f2bf(float f) {  // RNE bf16
  u32 x = __float_as_uint(f);
  u32 r = x + 0x7fffu + ((x >> 16) & 1u);
  return (u16)(r >> 16);
}
DEV float bf2f(u16 u) { return __uint_as_float(((u32)u) << 16); }
DEV u16 f2h(float f) {
  _Float16 h = (_Float16)f;
  u16 u;
  __builtin_memcpy(&u, &h, 2);
  return u;
}
DEV float tanh_pos(float n) {  // tanh for n >= 0
  float e = __builtin_amdgcn_exp2f(2.8853900817779268f * n);  // e^(2n)
  return (e - 1.f) / (e + 1.f);
}
DEV bf8_t conv8v(f4_t a, f4_t b, float f) {
  bf8_t o;
  o[0] = (short)f2bf(a[0] * f); o[1] = (short)f2bf(a[1] * f);
  o[2] = (short)f2bf(a[2] * f); o[3] = (short)f2bf(a[3] * f);
  o[4] = (short)f2bf(b[0] * f); o[5] = (short)f2bf(b[1] * f);
  o[6] = (short)f2bf(b[2] * f); o[7] = (short)f2bf(b[3] * f);
  return o;
}

// ---------------- prep: logmap0 rows (y=0..2) + weight bf16 conv (y=3) -----
__global__ __launch_bounds__(256) void prep(
    const float* __restrict__ q, const float* __restrict__ k,
    const float* __restrict__ v, const float* __restrict__ Wq,
    const float* __restrict__ Wk, const float* __restrict__ Wv,
    const float* __restrict__ Wo, u16* __restrict__ tanb,
    u16* __restrict__ Wbf) {
  const int y = blockIdx.y;
  if (y == 3) {
    const int x = blockIdx.x;  // 0..1023 -> 4 matrices x 256 blocks
    const int wi = x >> 8;
    const float* Wsel = wi == 0 ? Wq : (wi == 1 ? Wk : (wi == 2 ? Wv : Wo));
    const int idx = ((x & 255) * 256 + threadIdx.x) * 4;
    float4 val = *(const float4*)(Wsel + idx);
    ushort4 o;
    o.x = f2bf(val.x); o.y = f2bf(val.y); o.z = f2bf(val.z); o.w = f2bf(val.w);
    *(ushort4*)(Wbf + (size_t)wi * D * D + idx) = o;
    return;
  }
  const float* in = y == 0 ? q : (y == 1 ? k : v);
  u16* out = tanb + (size_t)y * BS * D;
  const int row = blockIdx.x;
  const float2 xv = *(const float2*)(in + (size_t)row * D + threadIdx.x * 2);
  float s = xv.x * xv.x + xv.y * xv.y;
  __shared__ float sh[4];
  float ws = waveSum(s);
  if ((threadIdx.x & 63) == 0) sh[threadIdx.x >> 6] = ws;
  __syncthreads();
  float tot = sh[0] + sh[1] + sh[2] + sh[3];
  float n = fmaxf(sqrtf(tot), EPSF);
  float z = fminf(n, 1.0f - EPSF);
  float fac = 0.34657359027997264f *
              __builtin_amdgcn_logf((1.0f + z) / (1.0f - z)) / n;
  ushort2 o;
  o.x = f2bf(xv.x * fac);
  o.y = f2bf(xv.y * fac);
  *(ushort2*)(out + (size_t)row * D + threadIdx.x * 2) = o;
}

// ---------------- QKV GEMM + fused expmap / V-transpose epilogues ----------
// z=0: q -> hq bf16 + qn2[H][BS] ; z=1: k -> hk + kn2 ; z=2: v -> vT f16.
__global__ __launch_bounds__(256) void gemm_qkv(
    const u16* __restrict__ tanb, const u16* __restrict__ Wbf,
    const float* __restrict__ bq, const float* __restrict__ bk,
    const float* __restrict__ bv, u16* __restrict__ hq, u16* __restrict__ hk,
    u16* __restrict__ vT, float* __restrict__ qn2, float* __restrict__ kn2) {
  const int z = blockIdx.z;
  const u16* A = tanb + (size_t)z * BS * D;
  const u16* W = Wbf + (size_t)z * D * D;
  const float* bias = z == 0 ? bq : (z == 1 ? bk : bv);
  const int i0 = blockIdx.y * 64, j0 = blockIdx.x * 64, h = blockIdx.x;
  __shared__ __align__(16) u16 As[4096], Bs[4096];
  const int tid = threadIdx.x;
  const int w = tid >> 6, l = tid & 63, lg = l >> 4, lr = l & 15;
  const int srow = tid >> 3, scb = tid & 7;
  f4_t acc[4] = {{0, 0, 0, 0}, {0, 0, 0, 0}, {0, 0, 0, 0}, {0, 0, 0, 0}};
  for (int kt = 0; kt < D; kt += 64) {
    bf8_t a0 = *(const bf8_t*)(A + (size_t)(i0 + srow) * D + kt + scb * 8);
    bf8_t a1 = *(const bf8_t*)(A + (size_t)(i0 + srow + 32) * D + kt + scb * 8);
    bf8_t w0 = *(const bf8_t*)(W + (size_t)(j0 + srow) * D + kt + scb * 8);
    bf8_t w1 = *(const bf8_t*)(W + (size_t)(j0 + srow + 32) * D + kt + scb * 8);
    __syncthreads();
    const int sw = 8 * (scb ^ (srow & 7));
    *(bf8_t*)&As[srow * 64 + sw] = a0;
    *(bf8_t*)&As[(srow + 32) * 64 + sw] = a1;
    *(bf8_t*)&Bs[srow * 64 + sw] = w0;
    *(bf8_t*)&Bs[(srow + 32) * 64 + sw] = w1;
    __syncthreads();
#pragma unroll
    for (int ks = 0; ks < 2; ++ks) {
      const int arow = w * 16 + lr;
      bf8_t af = *(const bf8_t*)&As[arow * 64 + 8 * ((ks * 4 + lg) ^ (arow & 7))];
#pragma unroll
      for (int nf = 0; nf < 4; ++nf) {
        const int brow = nf * 16 + lr;
        bf8_t bfr = *(const bf8_t*)&Bs[brow * 64 + 8 * ((ks * 4 + lg) ^ (brow & 7))];
        acc[nf] = __builtin_amdgcn_mfma_f32_16x16x32_bf16(af, bfr, acc[nf], 0, 0, 0);
      }
    }
  }
  float c[4][4];
#pragma unroll
  for (int nf = 0; nf < 4; ++nf) {
    const float bb = bias[j0 + nf * 16 + lr];
#pragma unroll
    for (int r = 0; r < 4; ++r) c[nf][r] = acc[nf][r] + bb;
  }
  if (z < 2) {
    float part[4] = {0, 0, 0, 0};
#pragma unroll
    for (int nf = 0; nf < 4; ++nf)
#pragma unroll
      for (int r = 0; r < 4; ++r) part[r] += c[nf][r] * c[nf][r];
#pragma unroll
    for (int off = 1; off < 16; off <<= 1)
#pragma unroll
      for (int r = 0; r < 4; ++r) part[r] += __shfl_xor(part[r], off, 64);
    float fac[4];
#pragma unroll
    for (int r = 0; r < 4; ++r) {
      float n = fmaxf(sqrtf(part[r]), EPSF);
      fac[r] = fminf(tanh_pos(n), MAXN) / n;
    }
    u16 yb[4][4];
    float p2[4] = {0, 0, 0, 0};
#pragma unroll
    for (int nf = 0; nf < 4; ++nf)
#pragma unroll
      for (int r = 0; r < 4; ++r) {
        u16 t = f2bf(c[nf][r] * fac[r]);
        yb[nf][r] = t;
        float yf = bf2f(t);
        p2[r] += yf * yf;  // norm^2 of the rounded point
      }
#pragma unroll
    for (int off = 1; off < 16; off <<= 1)
#pragma unroll
      for (int r = 0; r < 4; ++r) p2[r] += __shfl_xor(p2[r], off, 64);
    u16* dst = z == 0 ? hq : hk;
    float* n2o = z == 0 ? qn2 : kn2;
#pragma unroll
    for (int nf = 0; nf < 4; ++nf)
#pragma unroll
      for (int r = 0; r < 4; ++r)
        dst[(size_t)(i0 + w * 16 + lg * 4 + r) * D + j0 + nf * 16 + lr] = yb[nf][r];
    if (lr == 0)
#pragma unroll
      for (int r = 0; r < 4; ++r)
        n2o[h * BS + i0 + w * 16 + lg * 4 + r] = p2[r];
  } else {
    // V: f16, transpose via LDS -> vT[(b*8+h)*64 + d][s]
    __syncthreads();
#pragma unroll
    for (int nf = 0; nf < 4; ++nf)
#pragma unroll
      for (int r = 0; r < 4; ++r) {
        const int prow = w * 16 + lg * 4 + r;  // local token s
        const int pcol = nf * 16 + lr;         // local d
        As[prow * 64 + 8 * ((pcol >> 3) ^ (prow & 7)) + (pcol & 7)] = f2h(c[nf][r]);
      }
    __syncthreads();
    const int d = tid >> 2, s0 = (tid & 3) * 16;
    const int b = i0 >> 9, sb = (i0 & 511) + s0;
    bf8_t o0, o1;
#pragma unroll
    for (int j = 0; j < 8; ++j) {
      const int s = s0 + j;
      o0[j] = (short)As[s * 64 + 8 * ((d >> 3) ^ (s & 7)) + (d & 7)];
    }
#pragma unroll
    for (int j = 0; j < 8; ++j) {
      const int s = s0 + 8 + j;
      o1[j] = (short)As[s * 64 + 8 * ((d >> 3) ^ (s & 7)) + (d & 7)];
    }
    u16* dst = vT + ((size_t)((b * 8 + h) * 64 + d)) * S + sb;
    *(bf8_t*)dst = o0;
    *(bf8_t*)(dst + 8) = o1;
  }
}

// ---------------- fused attention, split-K x4, one wave / 16 Q-rows --------
// Block (0,0,0) zeroes rnorm[1024]+scnt[16] for the output stage.
__global__ __launch_bounds__(64) void fused_attn_sk(
    const u16* __restrict__ hq, const u16* __restrict__ hk,
    const u16* __restrict__ vT, const float* __restrict__ qn2,
    const float* __restrict__ kn2, float* __restrict__ Opart,
    float* __restrict__ rpart, float* __restrict__ rnz) {
  const int bh = blockIdx.z, b = bh >> 3, h = bh & 7;
  const int i0 = blockIdx.x * 16;
  const int sp = blockIdx.y;
  if (blockIdx.x == 0 && blockIdx.y == 0 && blockIdx.z == 0) {
    for (int e = threadIdx.x; e < 1040; e += 64) rnz[e] = 0.f;
  }
  __shared__ __align__(16) u16 Ps[2][16 * 64];
  const int l = threadIdx.x, lg = l >> 4, lr = l & 15;
  bf8_t qf[2];
#pragma unroll
  for (int ks = 0; ks < 2; ++ks)
    qf[ks] = *(const bf8_t*)(hq + (size_t)(b * S + i0 + lr) * D + h * 64 +
                             ks * 32 + lg * 8);
  float qq[4];
#pragma unroll
  for (int r = 0; r < 4; ++r) qq[r] = qn2[h * BS + b * S + i0 + lg * 4 + r];
  f4_t acc_o[4] = {{0, 0, 0, 0}, {0, 0, 0, 0}, {0, 0, 0, 0}, {0, 0, 0, 0}};
  float rsum[4] = {0, 0, 0, 0};
#pragma unroll
  for (int t = 0; t < 2; ++t) {
    const int kt = sp * 2 + t;
    const int kb = b * S + kt * 64;
    bf8_t kf[2][4], vf[2][4];
#pragma unroll
    for (int ks = 0; ks < 2; ++ks)
#pragma unroll
      for (int nf = 0; nf < 4; ++nf) {
        kf[ks][nf] = *(const bf8_t*)(hk + (size_t)(kb + nf * 16 + lr) * D +
                                     h * 64 + ks * 32 + lg * 8);
        vf[ks][nf] = *(const bf8_t*)(vT + (size_t)(bh * 64 + nf * 16 + lr) * S +
                                     kt * 64 + ks * 32 + lg * 8);
      }
    float kn[4];
#pragma unroll
    for (int nf = 0; nf < 4; ++nf) kn[nf] = kn2[h * BS + kb + nf * 16 + lr];
    f4_t sa[4] = {{0, 0, 0, 0}, {0, 0, 0, 0}, {0, 0, 0, 0}, {0, 0, 0, 0}};
#pragma unroll
    for (int ks = 0; ks < 2; ++ks)
#pragma unroll
      for (int nf = 0; nf < 4; ++nf)
        sa[nf] = __builtin_amdgcn_mfma_f32_16x16x32_bf16(qf[ks], kf[ks][nf],
                                                         sa[nf], 0, 0, 0);
    u16* Pb = Ps[t & 1];
    float ps[4] = {0, 0, 0, 0};
#pragma unroll
    for (int nf = 0; nf < 4; ++nf) {
      const float kk = kn[nf];
#pragma unroll
      for (int r = 0; r < 4; ++r) {
        const float tt = sa[nf][r];
        float num = fmaxf(qq[r] - 2.f * tt + kk, 0.f);
        float den = fmaxf(1.f - 2.f * tt + qq[r] * kk, EPSF);
        float rr = fminf(fmaxf(sqrtf(num / den), EPSF), MAXN);
        // p = ((1-r)/(1+r))^(1/8)
        float p = __builtin_amdgcn_exp2f(
            0.125f * __builtin_amdgcn_logf((1.f - rr) / (1.f + rr)));
        ps[r] += p;
        const int prow = lg * 4 + r, pcol = nf * 16 + lr;
        Pb[prow * 64 + 8 * ((pcol >> 3) ^ (prow & 7)) + (pcol & 7)] = f2h(p);
      }
    }
#pragma unroll
    for (int off = 1; off < 16; off <<= 1)
#pragma unroll
      for (int r = 0; r < 4; ++r) ps[r] += __shfl_xor(ps[r], off, 64);
#pragma unroll
    for (int r = 0; r < 4; ++r) rsum[r] += ps[r];
#pragma unroll
    for (int ks = 0; ks < 2; ++ks) {
      h8_t pa = *(const h8_t*)&Pb[lr * 64 + 8 * ((ks * 4 + lg) ^ (lr & 7))];
#pragma unroll
      for (int nf = 0; nf < 4; ++nf)
        acc_o[nf] = __builtin_amdgcn_mfma_f32_16x16x32_f16(pa, vf[ks][nf],
                                                           acc_o[nf], 0, 0, 0);
    }
  }
  float* Ob = Opart + ((size_t)(sp * 16 + bh) * S + i0) * 64;
#pragma unroll
  for (int nf = 0; nf < 4; ++nf)
#pragma unroll
    for (int r = 0; r < 4; ++r)
      Ob[(lg * 4 + r) * 64 + nf * 16 + lr] = acc_o[nf][r];
  if (lr == 0)
#pragma unroll
    for (int r = 0; r < 4; ++r)
      rpart[(size_t)(sp * 16 + bh) * S + i0 + lg * 4 + r] = rsum[r];
}

// ---------------- out GEMM: combine staging + bias + last-arriver expmap ---
// A-tile staged from Opart (4-split sum x 1/rsum -> bf16). After writing the
// olin tile + per-row norm^2 atomics, the 8th block of each row-slab rescales
// the slab (expmap0) into d_out. __threadfence() release/acquire around the
// scnt RMW (device-scope; validated in R7).
__global__ __launch_bounds__(256) void gemm_out_fin(
    const float* __restrict__ Opart, const float* __restrict__ rpart,
    const u16* __restrict__ Wo4, const float* __restrict__ bo,
    float* __restrict__ olin, float* __restrict__ rnorm,
    u32* __restrict__ scnt, float* __restrict__ out) {
  const int jblk = blockIdx.x, iblk = blockIdx.y;
  const int i0 = iblk * 64, j0 = jblk * 64;
  __shared__ __align__(16) u16 As[4096], Bs[4096];
  __shared__ float invs[512];
  __shared__ float facL[64];
  __shared__ int lastFlag;
  const int tid = threadIdx.x;
  const int w = tid >> 6, l = tid & 63, lg = l >> 4, lr = l & 15;
  const int srow = tid >> 3, scb = tid & 7;
  const int bb = i0 >> 9, sbase = i0 & 511;
  // prologue: per (head, row) inverse softmax sums for this token slab
  for (int e = tid; e < 512; e += 256) {
    const int h = e >> 6, sr = e & 63;
    const int bh = bb * 8 + h;
    float rt = 0.f;
#pragma unroll
    for (int sp = 0; sp < NSPLIT; ++sp)
      rt += rpart[(size_t)(sp * 16 + bh) * S + sbase + sr];
    invs[e] = 1.f / rt;
  }
  f4_t acc[4] = {{0, 0, 0, 0}, {0, 0, 0, 0}, {0, 0, 0, 0}, {0, 0, 0, 0}};
  for (int kt = 0; kt < 8; ++kt) {
    const int bh = bb * 8 + kt;  // A-cols kt*64.. are head kt
    const float* p0 = Opart + ((size_t)bh * S + sbase + srow) * 64 + scb * 8;
    f4_t s00 = {0, 0, 0, 0}, s01 = {0, 0, 0, 0};
    f4_t s10 = {0, 0, 0, 0}, s11 = {0, 0, 0, 0};
#pragma unroll
    for (int sp = 0; sp < NSPLIT; ++sp) {
      const float* p = p0 + (size_t)sp * 16 * S * 64;
      s00 += *(const f4_t*)p;
      s01 += *(const f4_t*)(p + 4);
      s10 += *(const f4_t*)(p + 32 * 64);
      s11 += *(const f4_t*)(p + 32 * 64 + 4);
    }
    const u16* wp = Wo4 + (size_t)(j0 + srow) * D + kt * 64 + scb * 8;
    bf8_t w0 = *(const bf8_t*)wp;
    bf8_t w1 = *(const bf8_t*)(wp + (size_t)32 * D);
    __syncthreads();  // prev iter LDS reads done; invs visible (iter 0)
    const float inv0 = invs[kt * 64 + srow], inv1 = invs[kt * 64 + srow + 32];
    const int sw = 8 * (scb ^ (srow & 7));
    *(bf8_t*)&As[srow * 64 + sw] = conv8v(s00, s01, inv0);
    *(bf8_t*)&As[(srow + 32) * 64 + sw] = conv8v(s10, s11, inv1);
    *(bf8_t*)&Bs[srow * 64 + sw] = w0;
    *(bf8_t*)&Bs[(srow + 32) * 64 + sw] = w1;
    __syncthreads();
#pragma unroll
    for (int ks = 0; ks < 2; ++ks) {
      const int arow = w * 16 + lr;
      bf8_t af = *(const bf8_t*)&As[arow * 64 + 8 * ((ks * 4 + lg) ^ (arow & 7))];
#pragma unroll
      for (int nf = 0; nf < 4; ++nf) {
        const int brow = nf * 16 + lr;
        bf8_t bfr = *(const bf8_t*)&Bs[brow * 64 + 8 * ((ks * 4 + lg) ^ (brow & 7))];
        acc[nf] = __builtin_amdgcn_mfma_f32_16x16x32_bf16(af, bfr, acc[nf], 0, 0, 0);
      }
    }
  }
  float c[4][4];
  float pr[4] = {0, 0, 0, 0};
#pragma unroll
  for (int nf = 0; nf < 4; ++nf) {
    const float bb2 = bo[j0 + nf * 16 + lr];
#pragma unroll
    for (int r = 0; r < 4; ++r) {
      c[nf][r] = acc[nf][r] + bb2;
      pr[r] += c[nf][r] * c[nf][r];
    }
  }
#pragma unroll
  for (int nf = 0; nf < 4; ++nf)
#pragma unroll
    for (int r = 0; r < 4; ++r)
      olin[(size_t)(i0 + w * 16 + lg * 4 + r) * D + j0 + nf * 16 + lr] = c[nf][r];
#pragma unroll
  for (int off = 1; off < 16; off <<= 1)
#pragma unroll
    for (int r = 0; r < 4; ++r) pr[r] += __shfl_xor(pr[r], off, 64);
  if (lr == 0)
#pragma unroll
    for (int r = 0; r < 4; ++r)
      atomicAdd(&rnorm[i0 + w * 16 + lg * 4 + r], pr[r]);
  __syncthreads();
  if (tid == 0) {
    __threadfence();  // release: olin stores + rnorm atomics visible
    u32 old = __hip_atomic_fetch_add(&scnt[iblk], 1u, __ATOMIC_ACQ_REL,
                                     __HIP_MEMORY_SCOPE_AGENT);
    lastFlag = (old == 7);
  }
  __syncthreads();
  if (!lastFlag) return;
  if (tid == 0) __threadfence();  // acquire side
  __syncthreads();
  if (tid < 64) {
    float nn = rnorm[i0 + tid];
    float n = fmaxf(sqrtf(nn), EPSF);
    facL[tid] = fminf(tanh_pos(n), MAXN) / n;
  }
  __syncthreads();
  for (int e = tid; e < 64 * 128; e += 256) {
    const int row = e >> 7, c4 = (e & 127) * 4;
    float4 t = *(const float4*)&olin[(size_t)(i0 + row) * D + c4];
    const float f = facL[row];
    float4 o = make_float4(t.x * f, t.y * f, t.z * f, t.w * f);
    *(float4*)&out[(size_t)(i0 + row) * D + c4] = o;
  }
}

}  // namespace

extern "C" void kernel_launch(void* const* d_in, const int* in_sizes, int n_in,
                              void* d_out, int out_size, void* d_ws,
                              size_t ws_size, hipStream_t stream) {
  const float* q = (const float*)d_in[0];
  const float* k = (const float*)d_in[1];
  const float* v = (const float*)d_in[2];
  const float* Wq = (const float*)d_in[3];
  const float* bq = (const float*)d_in[4];
  const float* Wk = (const float*)d_in[5];
  const float* bk = (const float*)d_in[6];
  const float* Wv = (const float*)d_in[7];
  const float* bv = (const float*)d_in[8];
  const float* Wo = (const float*)d_in[9];
  const float* bo = (const float*)d_in[10];
  float* out = (float*)d_out;

  char* w8 = (char*)d_ws;
  u16* tanb = (u16*)(w8 + 0);               // 3 MB   q|k|v tangent bf16
  u16* Wbf = (u16*)(w8 + 3145728);          // 2 MB   Wq|Wk|Wv|Wo bf16
  u16* hq = (u16*)(w8 + 5242880);           // 1 MB
  u16* hk = (u16*)(w8 + 6291456);           // 1 MB
  u16* vT = (u16*)(w8 + 7340032);           // 1 MB   [bh*64+d][s] f16
  float* qn2 = (float*)(w8 + 8388608);      // 32 KB  [H][BS]
  float* kn2 = (float*)(w8 + 8421376);      // 32 KB  [H][BS]
  float* olin = (float*)(w8 + 8454144);     // 2 MB   fp32
  float* Opart = (float*)(w8 + 10551296);   // 8 MB   [NSPLIT][16][512][64]
  float* rpart = (float*)(w8 + 18939904);   // 128 KB [NSPLIT][16][512]
  float* rnorm = (float*)(w8 + 19070976);   // 4 KB   [1024] (+scnt after)
  u32* scnt = (u32*)(w8 + 19075072);        // 64 B   [16]

  prep<<<dim3(BS, 4), 256, 0, stream>>>(q, k, v, Wq, Wk, Wv, Wo, tanb, Wbf);
  gemm_qkv<<<dim3(8, 16, 3), 256, 0, stream>>>(tanb, Wbf, bq, bk, bv, hq, hk,
                                               vT, qn2, kn2);
  fused_attn_sk<<<dim3(32, NSPLIT, 16), 64, 0, stream>>>(hq, hk, vT, qn2, kn2,
                                                         Opart, rpart, rnorm);
  gemm_out_fin<<<dim3(8, 16), 256, 0, stream>>>(Opart, rpart, Wbf + 3 * D * D,
                                                bo, olin, rnorm, scnt, out);
}